// Round 4
// baseline (182.181 us; speedup 1.0000x reference)
//
#include <hip/hip_runtime.h>
#include <math.h>

#define NROWS 1024
#define IN_DIM 256
#define OUT_DIM 128
#define D_ACT 64
#define NEG_SLOPE 0.01f

#define NBLOCKS 2048
#define NTHREADS 256
#define STRIDE (NBLOCKS * NTHREADS)        // 524288 threads
#define TOTAL4 (NROWS * NROWS * D_ACT / 4) // 16777216 float4s
#define BITERS (TOTAL4 / STRIDE)           // 32 iterations, exact

typedef float f4 __attribute__((ext_vector_type(4)));  // native vector: OK for nontemporal builtins

// ---------------------------------------------------------------------------
// K1: s_src[n] = h[n,:].(W_fc^T w_src), s_dst[n] = h[n,:].(W_fc^T w_dst)
// ---------------------------------------------------------------------------
__global__ __launch_bounds__(256) void compute_s_kernel(
    const float* __restrict__ h,
    const float* __restrict__ W_fc,
    const float* __restrict__ W_attn,
    float* __restrict__ s_src,
    float* __restrict__ s_dst) {
  const int n = blockIdx.x;
  const int m = threadIdx.x;

  float v_src = 0.f, v_dst = 0.f;
#pragma unroll 8
  for (int k = 0; k < OUT_DIM; ++k) {
    float w = W_fc[k * IN_DIM + m];
    v_src += w * W_attn[k];
    v_dst += w * W_attn[OUT_DIM + k];
  }
  const float hv = h[n * IN_DIM + m];
  float ps = hv * v_src;
  float pd = hv * v_dst;

  for (int off = 32; off > 0; off >>= 1) {
    ps += __shfl_down(ps, off, 64);
    pd += __shfl_down(pd, off, 64);
  }
  __shared__ float sm_s[4], sm_d[4];
  const int wave = m >> 6, lane = m & 63;
  if (lane == 0) { sm_s[wave] = ps; sm_d[wave] = pd; }
  __syncthreads();
  if (m == 0) {
    s_src[n] = sm_s[0] + sm_s[1] + sm_s[2] + sm_s[3];
    s_dst[n] = sm_d[0] + sm_d[1] + sm_d[2] + sm_d[3];
  }
}

// ---------------------------------------------------------------------------
// K2: per-row softmax stats; packs rowdat[i] = {s_dst[i], M_i, 1/denom_i, 0}
// ---------------------------------------------------------------------------
__global__ __launch_bounds__(256) void row_stats_kernel(
    const float* __restrict__ s_src,
    const float* __restrict__ s_dst,
    f4* __restrict__ rowdat) {
  const int i = blockIdx.x;
  const int t = threadIdx.x;
  const float sd = s_dst[i];

  float ev[4];
  float mx = -INFINITY;
#pragma unroll
  for (int r = 0; r < 4; ++r) {
    float e = sd + s_src[t + r * 256];
    e = e > 0.f ? e : NEG_SLOPE * e;
    ev[r] = e;
    mx = fmaxf(mx, e);
  }
  for (int off = 32; off > 0; off >>= 1) mx = fmaxf(mx, __shfl_down(mx, off, 64));

  __shared__ float sm[4];
  __shared__ float s_bcast;
  const int wave = t >> 6, lane = t & 63;
  if (lane == 0) sm[wave] = mx;
  __syncthreads();
  if (t == 0) s_bcast = fmaxf(fmaxf(sm[0], sm[1]), fmaxf(sm[2], sm[3]));
  __syncthreads();
  const float M = s_bcast;

  float sum = 0.f;
#pragma unroll
  for (int r = 0; r < 4; ++r) sum += __expf(ev[r] - M);
  for (int off = 32; off > 0; off >>= 1) sum += __shfl_down(sum, off, 64);

  __shared__ float ss[4];
  if (lane == 0) ss[wave] = sum;
  __syncthreads();
  if (t == 0) {
    f4 rd;
    rd.x = sd;
    rd.y = M;
    rd.z = 1.0f / (ss[0] + ss[1] + ss[2] + ss[3]);
    rd.w = 0.f;
    rowdat[i] = rd;
  }
}

// ---------------------------------------------------------------------------
// K3: streaming blend — m13-style grid-stride (compact moving access front),
// compile-time trip count (32), non-temporal store so the out stream doesn't
// write-allocate in L2/IC and evict input lines.
// ---------------------------------------------------------------------------
__global__ __launch_bounds__(256) void blend_kernel(
    const f4* __restrict__ action,
    const f4* __restrict__ policy,
    const f4* __restrict__ rowdat,
    const float* __restrict__ s_src,
    f4* __restrict__ out) {
  const int base = blockIdx.x * NTHREADS + threadIdx.x;
#pragma unroll 4
  for (int k = 0; k < BITERS; ++k) {
    const int t = base + k * STRIDE;
    const int p = t >> 4;          // (i,j) pair
    const int i = p >> 10;
    const int j = p & 1023;
    const f4 rd = rowdat[i];       // {s_dst, M, rdenom, -}
    float e = rd.x + s_src[j];
    e = e > 0.f ? e : NEG_SLOPE * e;
    const float alpha = __expf(e - rd.y) * rd.z;
    const f4 a = action[t];
    const f4 q = policy[t];
    f4 o = alpha * a + (1.f - alpha) * q;
    __builtin_nontemporal_store(o, &out[t]);
  }
}

extern "C" void kernel_launch(void* const* d_in, const int* in_sizes, int n_in,
                              void* d_out, int out_size, void* d_ws, size_t ws_size,
                              hipStream_t stream) {
  const float* h      = (const float*)d_in[0];
  const float* action = (const float*)d_in[1];
  const float* policy = (const float*)d_in[2];
  const float* W_fc   = (const float*)d_in[3];
  const float* W_attn = (const float*)d_in[4];
  float* out = (float*)d_out;

  // ws layout: s_src(1024) | s_dst(1024) | rowdat(1024 f4, 16B aligned at 8KiB)
  float* s_src  = (float*)d_ws;
  float* s_dst  = s_src + NROWS;
  f4* rowdat = (f4*)(s_dst + NROWS);

  compute_s_kernel<<<NROWS, 256, 0, stream>>>(h, W_fc, W_attn, s_src, s_dst);
  row_stats_kernel<<<NROWS, 256, 0, stream>>>(s_src, s_dst, rowdat);

  blend_kernel<<<NBLOCKS, NTHREADS, 0, stream>>>(
      (const f4*)action, (const f4*)policy,
      rowdat, s_src, (f4*)out);
}

// Round 5
// 165.384 us; speedup vs baseline: 1.1016x; 1.1016x over previous
//
#include <hip/hip_runtime.h>
#include <math.h>

#define NROWS 1024
#define IN_DIM 256
#define OUT_DIM 128
#define D_ACT 64
#define NEG_SLOPE 0.01f

#define ROW_T4 (NROWS * D_ACT / 4)        // 16384 float4 per row-block of pairs
#define SEGS_PER_ROW 8
#define SEG_T4 (ROW_T4 / SEGS_PER_ROW)    // 2048 float4 per block
#define SEG_PAIRS (NROWS / SEGS_PER_ROW)  // 128 (i,j) pairs per block

typedef float f4 __attribute__((ext_vector_type(4)));

// ---------------------------------------------------------------------------
// K1: s_src[n] = h[n,:].(W_fc^T w_src), s_dst[n] = h[n,:].(W_fc^T w_dst)
// ---------------------------------------------------------------------------
__global__ __launch_bounds__(256) void compute_s_kernel(
    const float* __restrict__ h,
    const float* __restrict__ W_fc,
    const float* __restrict__ W_attn,
    float* __restrict__ s_src,
    float* __restrict__ s_dst) {
  const int n = blockIdx.x;
  const int m = threadIdx.x;

  float v_src = 0.f, v_dst = 0.f;
#pragma unroll 8
  for (int k = 0; k < OUT_DIM; ++k) {
    float w = W_fc[k * IN_DIM + m];
    v_src += w * W_attn[k];
    v_dst += w * W_attn[OUT_DIM + k];
  }
  const float hv = h[n * IN_DIM + m];
  float ps = hv * v_src;
  float pd = hv * v_dst;

  for (int off = 32; off > 0; off >>= 1) {
    ps += __shfl_down(ps, off, 64);
    pd += __shfl_down(pd, off, 64);
  }
  __shared__ float sm_s[4], sm_d[4];
  const int wave = m >> 6, lane = m & 63;
  if (lane == 0) { sm_s[wave] = ps; sm_d[wave] = pd; }
  __syncthreads();
  if (m == 0) {
    s_src[n] = sm_s[0] + sm_s[1] + sm_s[2] + sm_s[3];
    s_dst[n] = sm_d[0] + sm_d[1] + sm_d[2] + sm_d[3];
  }
}

// ---------------------------------------------------------------------------
// K2: per-row softmax stats; rowdat[i] = {s_dst[i], M_i, 1/denom_i, 0}
// ---------------------------------------------------------------------------
__global__ __launch_bounds__(256) void row_stats_kernel(
    const float* __restrict__ s_src,
    const float* __restrict__ s_dst,
    f4* __restrict__ rowdat) {
  const int i = blockIdx.x;
  const int t = threadIdx.x;
  const float sd = s_dst[i];

  float ev[4];
  float mx = -INFINITY;
#pragma unroll
  for (int r = 0; r < 4; ++r) {
    float e = sd + s_src[t + r * 256];
    e = e > 0.f ? e : NEG_SLOPE * e;
    ev[r] = e;
    mx = fmaxf(mx, e);
  }
  for (int off = 32; off > 0; off >>= 1) mx = fmaxf(mx, __shfl_down(mx, off, 64));

  __shared__ float sm[4];
  __shared__ float s_bcast;
  const int wave = t >> 6, lane = t & 63;
  if (lane == 0) sm[wave] = mx;
  __syncthreads();
  if (t == 0) s_bcast = fmaxf(fmaxf(sm[0], sm[1]), fmaxf(sm[2], sm[3]));
  __syncthreads();
  const float M = s_bcast;

  float sum = 0.f;
#pragma unroll
  for (int r = 0; r < 4; ++r) sum += __expf(ev[r] - M);
  for (int off = 32; off > 0; off >>= 1) sum += __shfl_down(sum, off, 64);

  __shared__ float ss[4];
  if (lane == 0) ss[wave] = sum;
  __syncthreads();
  if (t == 0) {
    f4 rd;
    rd.x = sd;
    rd.y = M;
    rd.z = 1.0f / (ss[0] + ss[1] + ss[2] + ss[3]);
    rd.w = 0.f;
    rowdat[i] = rd;
  }
}

// ---------------------------------------------------------------------------
// K3: blend — R2's row-segment-pinned structure (best so far) + explicit
// 2-deep software pipeline: prefetch the next 2-iteration batch before
// computing the current one (max 8 f4 live = 32 data VGPRs, occupancy
// stays 8 waves/SIMD). Tests whether per-wave load serialization was the
// residual vs the mixed-stream BW wall. Plain stores (NT store regressed).
// ---------------------------------------------------------------------------
__global__ __launch_bounds__(256) void blend_kernel(
    const f4* __restrict__ action,
    const f4* __restrict__ policy,
    const f4* __restrict__ rowdat,
    const float* __restrict__ s_src,
    f4* __restrict__ out) {
  const int b = blockIdx.x;
  const int row = b >> 3;
  const int seg = b & 7;
  const int tid = threadIdx.x;

  __shared__ float alpha_lds[SEG_PAIRS];
  if (tid < SEG_PAIRS) {
    const f4 rd = rowdat[row];            // {s_dst, M, rdenom, -}
    float e = rd.x + s_src[seg * SEG_PAIRS + tid];
    e = e > 0.f ? e : NEG_SLOPE * e;
    alpha_lds[tid] = __expf(e - rd.y) * rd.z;
  }
  __syncthreads();

  const long base = (long)row * ROW_T4 + (long)seg * SEG_T4 + tid;
  const f4* __restrict__ ap = action + base;
  const f4* __restrict__ qp = policy + base;
  f4* __restrict__ op = out + base;
  const int ai = tid >> 4;   // alpha index for iter k is k*16 + ai
  float al;

  // batch 0 loads (iters 0,1)
  f4 a0 = ap[0],    q0 = qp[0];
  f4 a1 = ap[256],  q1 = qp[256];

  // prefetch batch 1 (iters 2,3), then compute batch 0
  f4 a2 = ap[512],  q2 = qp[512];
  f4 a3 = ap[768],  q3 = qp[768];
  al = alpha_lds[ai];       op[0]    = q0 + al * (a0 - q0);
  al = alpha_lds[16 + ai];  op[256]  = q1 + al * (a1 - q1);

  // prefetch batch 2 (iters 4,5), compute batch 1
  a0 = ap[1024]; q0 = qp[1024];
  a1 = ap[1280]; q1 = qp[1280];
  al = alpha_lds[32 + ai];  op[512]  = q2 + al * (a2 - q2);
  al = alpha_lds[48 + ai];  op[768]  = q3 + al * (a3 - q3);

  // prefetch batch 3 (iters 6,7), compute batch 2
  a2 = ap[1536]; q2 = qp[1536];
  a3 = ap[1792]; q3 = qp[1792];
  al = alpha_lds[64 + ai];  op[1024] = q0 + al * (a0 - q0);
  al = alpha_lds[80 + ai];  op[1280] = q1 + al * (a1 - q1);

  // compute batch 3
  al = alpha_lds[96 + ai];  op[1536] = q2 + al * (a2 - q2);
  al = alpha_lds[112 + ai]; op[1792] = q3 + al * (a3 - q3);
}

extern "C" void kernel_launch(void* const* d_in, const int* in_sizes, int n_in,
                              void* d_out, int out_size, void* d_ws, size_t ws_size,
                              hipStream_t stream) {
  const float* h      = (const float*)d_in[0];
  const float* action = (const float*)d_in[1];
  const float* policy = (const float*)d_in[2];
  const float* W_fc   = (const float*)d_in[3];
  const float* W_attn = (const float*)d_in[4];
  float* out = (float*)d_out;

  // ws layout: s_src(1024) | s_dst(1024) | rowdat(1024 f4, 16B-aligned @8KiB)
  float* s_src  = (float*)d_ws;
  float* s_dst  = s_src + NROWS;
  f4* rowdat = (f4*)(s_dst + NROWS);

  compute_s_kernel<<<NROWS, 256, 0, stream>>>(h, W_fc, W_attn, s_src, s_dst);
  row_stats_kernel<<<NROWS, 256, 0, stream>>>(s_src, s_dst, rowdat);

  blend_kernel<<<NROWS * SEGS_PER_ROW, 256, 0, stream>>>(
      (const f4*)action, (const f4*)policy,
      rowdat, s_src, (f4*)out);
}